// Round 2
// baseline (249.207 us; speedup 1.0000x reference)
//
#include <hip/hip_runtime.h>

#define N_ROWS    131072
#define D_IN      256
#define D_MID     128
#define N_SUBS    64
#define K1_BLOCKS 4096
#define ROWS_PER_WAVE (N_ROWS / (K1_BLOCKS * 4))   // 8 rows per wave

// ws layout: rowsum[N_ROWS] floats | gsum[64] | gcnt[64]

// 4096 blocks x 4 waves; each wave reduces 8 rows (256 floats each).
// 4 float4 loads in flight per thread (MLP), butterfly-reduce 4 rows at once,
// lane 0 stores a float4 of rowsums. Block 0 zeroes the group bins (consumed
// only by k2, which launches after this kernel drains -> no race).
__global__ __launch_bounds__(256) void k1_rowsum(const float* __restrict__ x,
                                                 float* __restrict__ rowsum,
                                                 float* __restrict__ bins) {
    if (blockIdx.x == 0 && threadIdx.x < 2 * N_SUBS) bins[threadIdx.x] = 0.0f;
    const int lane   = threadIdx.x & 63;
    const int waveId = blockIdx.x * 4 + (threadIdx.x >> 6);
    const int row0   = waveId * ROWS_PER_WAVE;
    const float4* __restrict__ xp = (const float4*)x;
    #pragma unroll
    for (int r = 0; r < ROWS_PER_WAVE; r += 4) {
        float4 a = xp[(size_t)(row0 + r + 0) * 64 + lane];
        float4 b = xp[(size_t)(row0 + r + 1) * 64 + lane];
        float4 c = xp[(size_t)(row0 + r + 2) * 64 + lane];
        float4 d = xp[(size_t)(row0 + r + 3) * 64 + lane];
        float s0 = (a.x + a.y) + (a.z + a.w);
        float s1 = (b.x + b.y) + (b.z + b.w);
        float s2 = (c.x + c.y) + (c.z + c.w);
        float s3 = (d.x + d.y) + (d.z + d.w);
        #pragma unroll
        for (int m = 32; m >= 1; m >>= 1) {
            s0 += __shfl_xor(s0, m, 64);
            s1 += __shfl_xor(s1, m, 64);
            s2 += __shfl_xor(s2, m, 64);
            s3 += __shfl_xor(s3, m, 64);
        }
        if (lane == 0)
            *(float4*)(rowsum + row0 + r) = make_float4(s0, s1, s2, s3);
    }
}

// 64 blocks grid-stride over rows; LDS 64-bin accumulate (shared atomics),
// then one global atomicAdd per bin per block (64x64 = 4096 atomics total).
__global__ __launch_bounds__(256) void k2_group(const float* __restrict__ rowsum,
                                                const int* __restrict__ sub,
                                                float* __restrict__ gsum,
                                                float* __restrict__ gcnt) {
    __shared__ float ls[N_SUBS];
    __shared__ float lc[N_SUBS];
    if (threadIdx.x < N_SUBS) { ls[threadIdx.x] = 0.0f; lc[threadIdx.x] = 0.0f; }
    __syncthreads();
    int stride = gridDim.x * blockDim.x;
    for (int i = blockIdx.x * blockDim.x + threadIdx.x; i < N_ROWS; i += stride) {
        int g = sub[i];
        atomicAdd(&ls[g], rowsum[i]);
        atomicAdd(&lc[g], 1.0f);
    }
    __syncthreads();
    if (threadIdx.x < N_SUBS) {
        atomicAdd(&gsum[threadIdx.x], ls[threadIdx.x]);
        atomicAdd(&gcnt[threadIdx.x], lc[threadIdx.x]);
    }
}

// 4096 blocks x 4 waves; each wave emits 8 output rows. Per row:
// o = relu(Lambda*(rowsum[i] + D_MID * s[sub[i]])), s[g] = relu(Gamma * mean).
__global__ __launch_bounds__(256) void k3_out(const float* __restrict__ rowsum,
                                              const int* __restrict__ sub,
                                              const float* __restrict__ gsum,
                                              const float* __restrict__ gcnt,
                                              const float* __restrict__ Gamma,
                                              const float* __restrict__ Lambda,
                                              float* __restrict__ out) {
    const int lane   = threadIdx.x & 63;
    const int waveId = blockIdx.x * 4 + (threadIdx.x >> 6);
    const int row0   = waveId * ROWS_PER_WAVE;
    const float G = Gamma[0], L = Lambda[0];
    const float rs0 = rowsum[0];   // empty-group fallback: sum over x[0]
    #pragma unroll
    for (int r = 0; r < ROWS_PER_WAVE; ++r) {
        const int row = row0 + r;
        const int g   = sub[row];
        const float c  = gcnt[g];
        const float ms = (c > 0.0f) ? (gsum[g] / c) : rs0;
        const float s  = fmaxf(G * ms, 0.0f);
        const float o  = fmaxf(L * (rowsum[row] + (float)D_MID * s), 0.0f);
        ((float4*)(out + (size_t)row * D_IN))[lane] = make_float4(o, o, o, o);
    }
}

extern "C" void kernel_launch(void* const* d_in, const int* in_sizes, int n_in,
                              void* d_out, int out_size, void* d_ws, size_t ws_size,
                              hipStream_t stream) {
    const float* x      = (const float*)d_in[0];
    const int*   sub    = (const int*)d_in[1];
    const float* Gamma  = (const float*)d_in[2];
    const float* Lambda = (const float*)d_in[3];
    float* out = (float*)d_out;

    float* rowsum = (float*)d_ws;            // N_ROWS floats
    float* gsum   = rowsum + N_ROWS;         // 64 floats
    float* gcnt   = gsum + N_SUBS;           // 64 floats

    k1_rowsum<<<K1_BLOCKS, 256, 0, stream>>>(x, rowsum, gsum);
    k2_group<<<64, 256, 0, stream>>>(rowsum, sub, gsum, gcnt);
    k3_out<<<K1_BLOCKS, 256, 0, stream>>>(rowsum, sub, gsum, gcnt, Gamma, Lambda, out);
}